// Round 5
// baseline (159.515 us; speedup 1.0000x reference)
//
#include <hip/hip_runtime.h>
#include <stdint.h>

typedef __attribute__((ext_vector_type(8))) short short8;
typedef __attribute__((ext_vector_type(4))) float f32x4;
typedef __attribute__((ext_vector_type(16))) float f32x16;
typedef __attribute__((ext_vector_type(4))) int i32x4;
typedef __attribute__((ext_vector_type(2))) int i32x2;

#define MFMA16(a, b, c) __builtin_amdgcn_mfma_f32_16x16x32_bf16((a), (b), (c), 0, 0, 0)
#define MFMA32(a, b, c) __builtin_amdgcn_mfma_f32_32x32x16_bf16((a), (b), (c), 0, 0, 0)

#define L2E 1.4426950408889634f

__device__ __forceinline__ unsigned short f2bf(float f) {
  unsigned int u = __builtin_bit_cast(unsigned int, f);
  u += 0x7fffu + ((u >> 16) & 1u);   // RNE (finite values only)
  return (unsigned short)(u >> 16);
}

// permlane32_swap via builtin: two simultaneously-live results -> the backend
// must use distinct registers (inline-asm "+v","+v" self-swap was R3's bug).
__device__ __forceinline__ i32x2 pls(int a, int b) {
  return __builtin_amdgcn_permlane32_swap(a, b, false, false);
}
__device__ __forceinline__ float fasf(int x) { return __builtin_bit_cast(float, x); }
__device__ __forceinline__ int iasi(float x) { return __builtin_bit_cast(int, x); }

__device__ __forceinline__ int cvtpk(float lo, float hi) {
  int d;
  asm("v_cvt_pk_bf16_f32 %0, %1, %2" : "=v"(d) : "v"(lo), "v"(hi));
  return d;
}

// ---------------------------------------------------------------------------
// Kernel 1: Q/K/V projections. Q pre-scaled by 1/sqrt(128). V stored transposed.
//   Qg,Kg: bf16 [B*S][128] row-major.  Vtg: bf16 [B][128][S].
// ---------------------------------------------------------------------------
__global__ __launch_bounds__(256) void k_proj(
    const float* __restrict__ x,
    const float* __restrict__ Wq, const float* __restrict__ bq,
    const float* __restrict__ Wk, const float* __restrict__ bk,
    const float* __restrict__ Wv, const float* __restrict__ bv,
    unsigned short* __restrict__ Qg, unsigned short* __restrict__ Kg,
    unsigned short* __restrict__ Vtg)
{
  __shared__ __align__(16) unsigned short wt[128 * 128];  // swizzled W^T, 32KB
  const int tid  = threadIdx.x;
  const int lane = tid & 63;
  const int wid  = tid >> 6;
  const int l15  = lane & 15;
  const int g    = lane >> 4;
  const int r0   = blockIdx.x * 64 + wid * 16;

  short8 af[4];
  {
    const float* xp = x + (r0 + l15) * 128 + g * 8;
#pragma unroll
    for (int kt = 0; kt < 4; ++kt) {
      float4 v0 = *(const float4*)(xp + kt * 32);
      float4 v1 = *(const float4*)(xp + kt * 32 + 4);
      short8 a;
      a[0] = (short)f2bf(v0.x); a[1] = (short)f2bf(v0.y);
      a[2] = (short)f2bf(v0.z); a[3] = (short)f2bf(v0.w);
      a[4] = (short)f2bf(v1.x); a[5] = (short)f2bf(v1.y);
      a[6] = (short)f2bf(v1.z); a[7] = (short)f2bf(v1.w);
      af[kt] = a;
    }
  }

  const float* Ws[3] = {Wq, Wk, Wv};
  const float* bs[3] = {bq, bk, bv};

  for (int wI = 0; wI < 3; ++wI) {
    __syncthreads();
    const float* W = Ws[wI];
    for (int i = 0; i < 64; ++i) {
      int idx = i * 256 + tid;
      int k = idx >> 7, n = idx & 127;
      int cs = (k >> 3) ^ (n & 7);
      wt[n * 128 + cs * 8 + (k & 7)] = f2bf(W[idx]);
    }
    __syncthreads();

    float bias[8];
#pragma unroll
    for (int nt = 0; nt < 8; ++nt) bias[nt] = bs[wI][nt * 16 + l15];

    f32x4 acc[8];
#pragma unroll
    for (int nt = 0; nt < 8; ++nt) acc[nt] = (f32x4){0.f, 0.f, 0.f, 0.f};

#pragma unroll
    for (int nt = 0; nt < 8; ++nt) {
      const int n = nt * 16 + l15;
#pragma unroll
      for (int ks = 0; ks < 4; ++ks) {
        int cs = (ks * 4 + g) ^ (n & 7);
        short8 bf = *(const short8*)&wt[n * 128 + cs * 8];
        acc[nt] = MFMA16(af[ks], bf, acc[nt]);
      }
    }

    if (wI < 2) {
      unsigned short* Og = (wI == 0) ? Qg : Kg;
      const float sc = (wI == 0) ? 0.08838834764831845f : 1.0f;  // 1/sqrt(128)
#pragma unroll
      for (int nt = 0; nt < 8; ++nt) {
        int col = nt * 16 + l15;
#pragma unroll
        for (int r = 0; r < 4; ++r) {
          int m = r0 + g * 4 + r;
          Og[m * 128 + col] = f2bf((acc[nt][r] + bias[nt]) * sc);
        }
      }
    } else {
#pragma unroll
      for (int nt = 0; nt < 8; ++nt) {
        int col = nt * 16 + l15;
        int m0 = r0 + g * 4;
        int bb = m0 >> 12, s0 = m0 & 4095;
        ushort4 pk;
        pk.x = f2bf(acc[nt][0] + bias[nt]);
        pk.y = f2bf(acc[nt][1] + bias[nt]);
        pk.z = f2bf(acc[nt][2] + bias[nt]);
        pk.w = f2bf(acc[nt][3] + bias[nt]);
        *(ushort4*)&Vtg[(bb * 128 + col) * 4096 + s0] = pk;
      }
    }
  }
}

// ---------------------------------------------------------------------------
// Kernel 2: flash attention, 8 waves (512 thr) per block, 1 block/CU.
// Block = 64 q-rows x full KV. wave = (qsub = wid>>2, kvsub = wid&3):
//   32 q x 1024 kv, KVBLK=32, 32 iters.
// K/V loaded DIRECTLY global->VGPR (no LDS staging; each element used once
// per wave). Single-buffered frags, issue-after-death prefetch, compiler-
// managed waitcnts. Raw s_barrier per iter keeps the 2 qsub-waves of each
// kvsub stream temporally aligned for L1 dedup.
// Swapped QK^T 32x32x16: lane = q, regs = kv. Softmax + P fully in-register.
// LDS only: merge chunks 24KB + (m,l) + bcast buffers = ~28KB.
// ---------------------------------------------------------------------------
#define MOOFF 0
#define MLOFF 24576
#define CBUF  26112
#define RB2   27136
#define RBUF  27392

__global__ __launch_bounds__(512, 2) void k_attn(
    const unsigned short* __restrict__ Qg,
    const unsigned short* __restrict__ Kg,
    const unsigned short* __restrict__ Vtg,
    unsigned short* __restrict__ Ag)
{
  __shared__ __align__(16) char smem[28672];
  const int tid = threadIdx.x, lane = tid & 63, wid = tid >> 6;
  const int rr = lane & 31, hi = lane >> 5;
  const int qsub = wid >> 2, kvsub = wid & 3;
  // XCD-aware: batch b pinned to XCD pair {2b,2b+1}
  const int p = blockIdx.x;
  const int b = (p & 7) >> 1;
  const int qt = ((p >> 3) << 1) | (p & 1);     // 0..63
  const int q0 = qt * 64 + qsub * 32;
  const int kv0 = kvsub * 1024;

  // Q fragments (pre-scaled): B-operand, col=q=rr, k = kt*16 + hi*8 + j
  short8 qf[8];
  {
    const unsigned short* qp = Qg + (b * 4096 + q0 + rr) * 128 + hi * 8;
#pragma unroll
    for (int kt = 0; kt < 8; ++kt) qf[kt] = *(const short8*)(qp + kt * 16);
  }

  // direct-load base pointers (advance per iter)
  const unsigned short* kp = Kg + (size_t)(b * 4096 + kv0 + rr) * 128 + hi * 8;
  const unsigned short* vp = Vtg + (size_t)(b * 128 + rr) * 4096 + kv0 + hi * 8;

  short8 kf[8], vf[2][4];
#pragma unroll
  for (int kt = 0; kt < 8; ++kt) kf[kt] = *(const short8*)(kp + kt * 16);
#pragma unroll
  for (int kt = 0; kt < 2; ++kt)
#pragma unroll
    for (int dt = 0; dt < 4; ++dt)
      vf[kt][dt] = *(const short8*)(vp + dt * 131072 + kt * 16);
  kp += 4096;   // 32 rows * 128
  vp += 32;     // s += 32

  f32x16 O[4];
#pragma unroll
  for (int dt = 0; dt < 4; ++dt)
#pragma unroll
    for (int j = 0; j < 16; ++j) O[dt][j] = 0.f;
  float mS = -3.0e38f, lS = 0.f;

  for (int t = 0; t < 32; ++t) {
    // ---- QK^T swapped: D[kv=regs][q=lane&31], two accumulator chains ----
    f32x16 sa = {0,0,0,0,0,0,0,0,0,0,0,0,0,0,0,0};
    f32x16 sb = {0,0,0,0,0,0,0,0,0,0,0,0,0,0,0,0};
    __builtin_amdgcn_s_setprio(1);
#pragma unroll
    for (int kt = 0; kt < 4; ++kt) sa = MFMA32(kf[kt], qf[kt], sa);
#pragma unroll
    for (int kt = 4; kt < 8; ++kt) sb = MFMA32(kf[kt], qf[kt], sb);
    __builtin_amdgcn_s_setprio(0);

    // prefetch next K tile into kf (regs dead after QK^T; WAR keeps order)
    if (t < 31) {
#pragma unroll
      for (int kt = 0; kt < 8; ++kt) kf[kt] = *(const short8*)(kp + kt * 16);
    }
    __builtin_amdgcn_s_barrier();   // loose temporal alignment (L1 dedup); no fence

    f32x16 sT = sa + sb;

    // ---- online softmax, in-register; kv row of reg r = (r&3)+8*(r>>2)+4*hi ----
    float pm = fmaxf(fmaxf(fmaxf(sT[0], sT[1]), fmaxf(sT[2], sT[3])),
                     fmaxf(fmaxf(sT[4], sT[5]), fmaxf(sT[6], sT[7])));
    pm = fmaxf(pm, fmaxf(fmaxf(fmaxf(sT[8], sT[9]), fmaxf(sT[10], sT[11])),
                         fmaxf(fmaxf(sT[12], sT[13]), fmaxf(sT[14], sT[15]))));
    { i32x2 r = pls(iasi(pm), iasi(pm)); pm = fmaxf(fasf(r[0]), fasf(r[1])); }

    if (!__all(pm - mS <= 8.0f)) {          // defer-max (THR=8)
      float mnew = fmaxf(mS, pm);
      float fsc = exp2f((mS - mnew) * L2E);
      mS = mnew;
      lS *= fsc;
      // redistribute fsc from lane-q to reg-rows via wave-private LDS broadcast
      if (hi == 0) *(float*)(smem + RBUF + wid * 128 + rr * 4) = fsc;
      f32x4 fr[4];
#pragma unroll
      for (int i = 0; i < 4; ++i)
        fr[i] = *(const f32x4*)(smem + RBUF + wid * 128 + i * 32 + hi * 16);
#pragma unroll
      for (int dt = 0; dt < 4; ++dt)
#pragma unroll
        for (int i = 0; i < 4; ++i)
#pragma unroll
          for (int j = 0; j < 4; ++j) O[dt][i * 4 + j] *= fr[i][j];
    }

    const float mL = mS * L2E;
    float pv[16];
#pragma unroll
    for (int r = 0; r < 16; ++r) pv[r] = exp2f(sT[r] * L2E - mL);
    // tree sum
    float s01 = (pv[0] + pv[1]) + (pv[2] + pv[3]);
    float s23 = (pv[4] + pv[5]) + (pv[6] + pv[7]);
    float s45 = (pv[8] + pv[9]) + (pv[10] + pv[11]);
    float s67 = (pv[12] + pv[13]) + (pv[14] + pv[15]);
    float ts = (s01 + s23) + (s45 + s67);
    { i32x2 r = pls(iasi(ts), iasi(ts)); ts = fasf(r[0]) + fasf(r[1]); }
    lS += ts;

    // ---- P -> PV A-fragments fully in registers (T12) ----
    int dw[8];
#pragma unroll
    for (int m = 0; m < 8; ++m) dw[m] = cvtpk(pv[2 * m], pv[2 * m + 1]);
    i32x2 ra = pls(dw[0], dw[2]);
    i32x2 rb = pls(dw[1], dw[3]);
    i32x2 rc = pls(dw[4], dw[6]);
    i32x2 rd = pls(dw[5], dw[7]);
    i32x4 w0 = {ra[0], rb[0], ra[1], rb[1]};
    i32x4 w1 = {rc[0], rd[0], rc[1], rd[1]};
    short8 pa0 = __builtin_bit_cast(short8, w0);
    short8 pa1 = __builtin_bit_cast(short8, w1);

    // ---- PV: O[q][d] += P[q][kv] * V[kv][d] ----
    __builtin_amdgcn_s_setprio(1);
#pragma unroll
    for (int dt = 0; dt < 4; ++dt) {
      O[dt] = MFMA32(pa0, vf[0][dt], O[dt]);
      O[dt] = MFMA32(pa1, vf[1][dt], O[dt]);
    }
    __builtin_amdgcn_s_setprio(0);

    // prefetch next V tile into vf; advance pointers
    if (t < 31) {
#pragma unroll
      for (int kt = 0; kt < 2; ++kt)
#pragma unroll
        for (int dt = 0; dt < 4; ++dt)
          vf[kt][dt] = *(const short8*)(vp + dt * 131072 + kt * 16);
      kp += 4096;
      vp += 32;
    }
  }

  // ---- in-LDS merge of the 4 kv-splits (per qsub group), chunked by dt ----
  if (kvsub != 0 && hi == 0)
    *(float2*)(smem + MLOFF + (qsub * 3 + kvsub - 1) * 256 + rr * 8) =
        make_float2(mS, lS);
  __syncthreads();

  f32x4 crh[4][4], irv[4];
  if (kvsub == 0) {
    float mh[4], lh[4];
    mh[0] = mS; lh[0] = lS;
#pragma unroll
    for (int h = 1; h < 4; ++h) {
      float2 ml = *(const float2*)(smem + MLOFF + (qsub * 3 + h - 1) * 256 + rr * 8);
      mh[h] = ml.x; lh[h] = ml.y;
    }
    float M = fmaxf(fmaxf(mh[0], mh[1]), fmaxf(mh[2], mh[3]));
    float c[4], L = 0.f;
#pragma unroll
    for (int h = 0; h < 4; ++h) { c[h] = exp2f((mh[h] - M) * L2E); L += c[h] * lh[h]; }
    float iL = 1.0f / L;
    if (hi == 0) {
#pragma unroll
      for (int h = 0; h < 4; ++h)
        *(float*)(smem + CBUF + qsub * 512 + h * 128 + rr * 4) = c[h];
      *(float*)(smem + RB2 + qsub * 128 + rr * 4) = iL;
    }
#pragma unroll
    for (int i = 0; i < 4; ++i) {
#pragma unroll
      for (int h = 0; h < 4; ++h)
        crh[h][i] = *(const f32x4*)(smem + CBUF + qsub * 512 + h * 128 + i * 32 + hi * 16);
      irv[i] = *(const f32x4*)(smem + RB2 + qsub * 128 + i * 32 + hi * 16);
    }
  }

  unsigned short* og = Ag + (size_t)(b * 4096 + q0) * 128;
#pragma unroll
  for (int dt = 0; dt < 4; ++dt) {
    if (kvsub != 0) {
#pragma unroll
      for (int i = 0; i < 4; ++i) {
        f32x4 s = {O[dt][4 * i], O[dt][4 * i + 1], O[dt][4 * i + 2], O[dt][4 * i + 3]};
        *(f32x4*)(smem + MOOFF + (qsub * 3 + kvsub - 1) * 4096 + i * 1024 + lane * 16) = s;
      }
    }
    __syncthreads();
    if (kvsub == 0) {
#pragma unroll
      for (int i = 0; i < 4; ++i) {
        f32x4 o1 = *(const f32x4*)(smem + MOOFF + (qsub * 3 + 0) * 4096 + i * 1024 + lane * 16);
        f32x4 o2 = *(const f32x4*)(smem + MOOFF + (qsub * 3 + 1) * 4096 + i * 1024 + lane * 16);
        f32x4 o3 = *(const f32x4*)(smem + MOOFF + (qsub * 3 + 2) * 4096 + i * 1024 + lane * 16);
#pragma unroll
        for (int j = 0; j < 4; ++j) {
          float v = (crh[0][i][j] * O[dt][4 * i + j] + crh[1][i][j] * o1[j] +
                     crh[2][i][j] * o2[j] + crh[3][i][j] * o3[j]) * irv[i][j];
          int row = j + 8 * i + 4 * hi;
          og[row * 128 + dt * 32 + rr] = f2bf(v);
        }
      }
    }
    __syncthreads();
  }
}

// ---------------------------------------------------------------------------
// Kernel 3: out = attended @ Wo + bo  (fp32 output)
// ---------------------------------------------------------------------------
__global__ __launch_bounds__(256) void k_out(
    const unsigned short* __restrict__ Ag,
    const float* __restrict__ Wo, const float* __restrict__ bo,
    float* __restrict__ out)
{
  __shared__ __align__(16) unsigned short wt[128 * 128];
  const int tid = threadIdx.x, lane = tid & 63, wid = tid >> 6;
  const int l15 = lane & 15, g = lane >> 4;
  const int r0 = blockIdx.x * 64 + wid * 16;

  for (int i = 0; i < 64; ++i) {
    int idx = i * 256 + tid;
    int k = idx >> 7, n = idx & 127;
    int cs = (k >> 3) ^ (n & 7);
    wt[n * 128 + cs * 8 + (k & 7)] = f2bf(Wo[idx]);
  }

  short8 af[4];
  const unsigned short* ap = Ag + (r0 + l15) * 128 + g * 8;
#pragma unroll
  for (int kt = 0; kt < 4; ++kt) af[kt] = *(const short8*)(ap + kt * 32);

  float bias[8];
#pragma unroll
  for (int nt = 0; nt < 8; ++nt) bias[nt] = bo[nt * 16 + l15];

  __syncthreads();

  f32x4 acc[8];
#pragma unroll
  for (int nt = 0; nt < 8; ++nt) acc[nt] = (f32x4){0.f, 0.f, 0.f, 0.f};
#pragma unroll
  for (int nt = 0; nt < 8; ++nt) {
    int n = nt * 16 + l15;
#pragma unroll
    for (int ks = 0; ks < 4; ++ks) {
      int cs = (ks * 4 + g) ^ (n & 7);
      short8 bf = *(const short8*)&wt[n * 128 + cs * 8];
      acc[nt] = MFMA16(af[ks], bf, acc[nt]);
    }
  }
#pragma unroll
  for (int nt = 0; nt < 8; ++nt) {
    int col = nt * 16 + l15;
#pragma unroll
    for (int r = 0; r < 4; ++r)
      out[(r0 + g * 4 + r) * 128 + col] = acc[nt][r] + bias[nt];
  }
}

// ---------------------------------------------------------------------------
extern "C" void kernel_launch(void* const* d_in, const int* in_sizes, int n_in,
                              void* d_out, int out_size, void* d_ws, size_t ws_size,
                              hipStream_t stream) {
  const float* x  = (const float*)d_in[0];
  const float* Wq = (const float*)d_in[1];
  const float* bq = (const float*)d_in[2];
  const float* Wk = (const float*)d_in[3];
  const float* bk = (const float*)d_in[4];
  const float* Wv = (const float*)d_in[5];
  const float* bv = (const float*)d_in[6];
  const float* Wo = (const float*)d_in[7];
  const float* bo = (const float*)d_in[8];

  const int NTOK = 4 * 4096;               // B*S
  unsigned short* Qg  = (unsigned short*)d_ws;
  unsigned short* Kg  = Qg  + NTOK * 128;
  unsigned short* Vtg = Kg  + NTOK * 128;
  unsigned short* Ag  = Vtg + NTOK * 128;  // total 16 MB of d_ws

  k_proj<<<256, 256, 0, stream>>>(x, Wq, bq, Wk, bk, Wv, bv, Qg, Kg, Vtg);
  k_attn<<<256, 512, 0, stream>>>(Qg, Kg, Vtg, Ag);
  k_out<<<256, 256, 0, stream>>>(Ag, Wo, bo, (float*)d_out);
}

// Round 6
// 95.406 us; speedup vs baseline: 1.6720x; 1.6720x over previous
//
#include <hip/hip_runtime.h>
#include <stdint.h>

typedef __attribute__((ext_vector_type(8))) short short8;
typedef __attribute__((ext_vector_type(4))) float f32x4;
typedef __attribute__((ext_vector_type(16))) float f32x16;
typedef __attribute__((ext_vector_type(4))) int i32x4;
typedef __attribute__((ext_vector_type(2))) int i32x2;

#define MFMA16(a, b, c) __builtin_amdgcn_mfma_f32_16x16x32_bf16((a), (b), (c), 0, 0, 0)
#define MFMA32(a, b, c) __builtin_amdgcn_mfma_f32_32x32x16_bf16((a), (b), (c), 0, 0, 0)

typedef __attribute__((address_space(1))) const void GVoid;
typedef __attribute__((address_space(3))) void LVoid;
#define GLDS16(g, l) __builtin_amdgcn_global_load_lds((GVoid*)(g), (LVoid*)(l), 16, 0, 0)

#define L2E 1.4426950408889634f

__device__ __forceinline__ unsigned short f2bf(float f) {
  unsigned int u = __builtin_bit_cast(unsigned int, f);
  u += 0x7fffu + ((u >> 16) & 1u);   // RNE (finite values only)
  return (unsigned short)(u >> 16);
}

// permlane32_swap via builtin: two simultaneously-live results -> the backend
// must use distinct registers (inline-asm "+v","+v" self-swap was R3's bug).
__device__ __forceinline__ i32x2 pls(int a, int b) {
  return __builtin_amdgcn_permlane32_swap(a, b, false, false);
}
__device__ __forceinline__ float fasf(int x) { return __builtin_bit_cast(float, x); }
__device__ __forceinline__ int iasi(float x) { return __builtin_bit_cast(int, x); }

__device__ __forceinline__ int cvtpk(float lo, float hi) {
  int d;
  asm("v_cvt_pk_bf16_f32 %0, %1, %2" : "=v"(d) : "v"(lo), "v"(hi));
  return d;
}

// ---------------------------------------------------------------------------
// Kernel 1: Q/K/V projections. Q pre-scaled by 1/sqrt(128). V stored transposed.
//   Qg,Kg: bf16 [B*S][128] row-major.  Vtg: bf16 [B][128][S].
// ---------------------------------------------------------------------------
__global__ __launch_bounds__(256) void k_proj(
    const float* __restrict__ x,
    const float* __restrict__ Wq, const float* __restrict__ bq,
    const float* __restrict__ Wk, const float* __restrict__ bk,
    const float* __restrict__ Wv, const float* __restrict__ bv,
    unsigned short* __restrict__ Qg, unsigned short* __restrict__ Kg,
    unsigned short* __restrict__ Vtg)
{
  __shared__ __align__(16) unsigned short wt[128 * 128];  // swizzled W^T, 32KB
  const int tid  = threadIdx.x;
  const int lane = tid & 63;
  const int wid  = tid >> 6;
  const int l15  = lane & 15;
  const int g    = lane >> 4;
  const int r0   = blockIdx.x * 64 + wid * 16;

  short8 af[4];
  {
    const float* xp = x + (r0 + l15) * 128 + g * 8;
#pragma unroll
    for (int kt = 0; kt < 4; ++kt) {
      float4 v0 = *(const float4*)(xp + kt * 32);
      float4 v1 = *(const float4*)(xp + kt * 32 + 4);
      short8 a;
      a[0] = (short)f2bf(v0.x); a[1] = (short)f2bf(v0.y);
      a[2] = (short)f2bf(v0.z); a[3] = (short)f2bf(v0.w);
      a[4] = (short)f2bf(v1.x); a[5] = (short)f2bf(v1.y);
      a[6] = (short)f2bf(v1.z); a[7] = (short)f2bf(v1.w);
      af[kt] = a;
    }
  }

  const float* Ws[3] = {Wq, Wk, Wv};
  const float* bs[3] = {bq, bk, bv};

  for (int wI = 0; wI < 3; ++wI) {
    __syncthreads();
    const float* W = Ws[wI];
    for (int i = 0; i < 64; ++i) {
      int idx = i * 256 + tid;
      int k = idx >> 7, n = idx & 127;
      int cs = (k >> 3) ^ (n & 7);
      wt[n * 128 + cs * 8 + (k & 7)] = f2bf(W[idx]);
    }
    __syncthreads();

    float bias[8];
#pragma unroll
    for (int nt = 0; nt < 8; ++nt) bias[nt] = bs[wI][nt * 16 + l15];

    f32x4 acc[8];
#pragma unroll
    for (int nt = 0; nt < 8; ++nt) acc[nt] = (f32x4){0.f, 0.f, 0.f, 0.f};

#pragma unroll
    for (int nt = 0; nt < 8; ++nt) {
      const int n = nt * 16 + l15;
#pragma unroll
      for (int ks = 0; ks < 4; ++ks) {
        int cs = (ks * 4 + g) ^ (n & 7);
        short8 bf = *(const short8*)&wt[n * 128 + cs * 8];
        acc[nt] = MFMA16(af[ks], bf, acc[nt]);
      }
    }

    if (wI < 2) {
      unsigned short* Og = (wI == 0) ? Qg : Kg;
      const float sc = (wI == 0) ? 0.08838834764831845f : 1.0f;  // 1/sqrt(128)
#pragma unroll
      for (int nt = 0; nt < 8; ++nt) {
        int col = nt * 16 + l15;
#pragma unroll
        for (int r = 0; r < 4; ++r) {
          int m = r0 + g * 4 + r;
          Og[m * 128 + col] = f2bf((acc[nt][r] + bias[nt]) * sc);
        }
      }
    } else {
#pragma unroll
      for (int nt = 0; nt < 8; ++nt) {
        int col = nt * 16 + l15;
        int m0 = r0 + g * 4;
        int bb = m0 >> 12, s0 = m0 & 4095;
        ushort4 pk;
        pk.x = f2bf(acc[nt][0] + bias[nt]);
        pk.y = f2bf(acc[nt][1] + bias[nt]);
        pk.z = f2bf(acc[nt][2] + bias[nt]);
        pk.w = f2bf(acc[nt][3] + bias[nt]);
        *(ushort4*)&Vtg[(bb * 128 + col) * 4096 + s0] = pk;
      }
    }
  }
}

// ---------------------------------------------------------------------------
// Kernel 2: flash attention, 8 waves (512 thr) per block, 1 block/CU.
// Block = 64 q-rows x full KV. wave = (qsub = wid>>2, kvsub = wid&3):
//   32 q x 1024-kv quarter, KVBLK=32, 32 iters.
// The 2 qsub waves of each kvsub SHARE one staged K/V tile: qs=0 stages K,
// qs=1 stages V (8 GLDS16 each). Double-buffered; stage(t+1) issued right
// after the iter-top __syncthreads (implicit vmcnt(0) = cross-wave landing
// guarantee) -> full-iter latency cover, one barrier/iter.
// Swapped QK^T 32x32x16: lane = q, regs = kv; single accumulator chain.
// Softmax + P fully in-register (cvt_pk + permlane32_swap), defer-max.
// LDS: [4 kvsub][2 dbuf][K 8KB | V 8KB] = 128KB; RBUFL 1KB; merge overlays
// staging region after the loop (guard barrier first).
// ---------------------------------------------------------------------------
#define RBUFL 131072
#define MOOFF 0
#define MLOFF 24576
#define CBUF  26112
#define RB2   27136

__global__ __launch_bounds__(512, 2) void k_attn(
    const unsigned short* __restrict__ Qg,
    const unsigned short* __restrict__ Kg,
    const unsigned short* __restrict__ Vtg,
    unsigned short* __restrict__ Ag)
{
  __shared__ __align__(16) char smem[132096];
  const int tid = threadIdx.x, lane = tid & 63, wid = tid >> 6;
  const int rr = lane & 31, hi = lane >> 5;
  const int qsub = wid >> 2, kvsub = wid & 3;
  // XCD-aware: batch b pinned to XCD pair {2b,2b+1}
  const int p = blockIdx.x;
  const int b = (p & 7) >> 1;
  const int qt = ((p >> 3) << 1) | (p & 1);     // 0..63
  const int q0 = qt * 64 + qsub * 32;
  const int kv0 = kvsub * 1024;

  // Q fragments (pre-scaled): B-operand, col=q=rr, k = kt*16 + hi*8 + j
  short8 qf[8];
  {
    const unsigned short* qp = Qg + (b * 4096 + q0 + rr) * 128 + hi * 8;
#pragma unroll
    for (int kt = 0; kt < 8; ++kt) qf[kt] = *(const short8*)(qp + kt * 16);
  }

  // staging source element-offsets (pre-swizzled; linear GLDS dest = swizzled image)
  int koff[8], voff[8];
#pragma unroll
  for (int i = 0; i < 8; ++i) {
    int D = i * 1024 + lane * 16;
    int krow = D >> 8, kcp = (D >> 4) & 15;
    koff[i] = (b * 4096 + kv0 + krow) * 128 + (kcp ^ (krow & 15)) * 8;
    int dp = D >> 7, vcp = (D >> 4) & 7;
    int cl = vcp ^ (dp & 7);
    voff[i] = (b * 128 + dp * 2 + (cl >> 2)) * 4096 + kv0 + ((cl >> 1) & 1) * 16 + (cl & 1) * 8;
  }
  // fragment read LDS byte-offsets (constant across iterations)
  int kfo[8];
#pragma unroll
  for (int kt = 0; kt < 8; ++kt) kfo[kt] = rr * 256 + (((kt * 2 + hi) ^ (rr & 15)) << 4);
  int vfo[2];
#pragma unroll
  for (int kt = 0; kt < 2; ++kt)
    vfo[kt] = (rr >> 1) * 128 + ((((rr & 1) * 4 + kt * 2 + hi) ^ ((rr >> 1) & 7)) << 4);

  // wave (qs,kvs): qs=0 stages the K tile, qs=1 stages the V tile (8KB each)
  auto stage = [&](int t, int d) {
    char* dst = smem + kvsub * 32768 + d * 16384 + (qsub ? 8192 : 0);
    if (qsub == 0) {
      const int tk = t * 4096;
#pragma unroll
      for (int i = 0; i < 8; ++i) GLDS16(Kg + koff[i] + tk, dst + i * 1024 + lane * 16);
    } else {
      const int tv = t * 32;
#pragma unroll
      for (int i = 0; i < 8; ++i) GLDS16(Vtg + voff[i] + tv, dst + i * 1024 + lane * 16);
    }
  };

  stage(0, 0);

  f32x16 O[4];
#pragma unroll
  for (int dt = 0; dt < 4; ++dt)
#pragma unroll
    for (int j = 0; j < 16; ++j) O[dt][j] = 0.f;
  f32x16 zc;
#pragma unroll
  for (int j = 0; j < 16; ++j) zc[j] = 0.f;
  float mS = -3.0e38f, lS = 0.f;

  int cur = 0;
  for (int t = 0; t < 32; ++t) {
    // implicit s_waitcnt vmcnt(0) + barrier: ALL waves' stage(t) writes landed;
    // also guarantees buf[cur^1] readers (tile t-1) are done -> safe to restage.
    __syncthreads();
    if (t < 31) stage(t + 1, cur ^ 1);

    const char* kb = smem + kvsub * 32768 + cur * 16384;
    short8 kf[8];
#pragma unroll
    for (int kt = 0; kt < 8; ++kt) kf[kt] = *(const short8*)(kb + kfo[kt]);

    // ---- QK^T swapped: D[kv=regs][q=lane&31], single accumulator chain ----
    __builtin_amdgcn_s_setprio(1);
    f32x16 sT = MFMA32(kf[0], qf[0], zc);
#pragma unroll
    for (int kt = 1; kt < 8; ++kt) sT = MFMA32(kf[kt], qf[kt], sT);
    __builtin_amdgcn_s_setprio(0);

    // ---- online softmax, in-register; kv row of reg r = (r&3)+8*(r>>2)+4*hi ----
    float pm = fmaxf(fmaxf(fmaxf(sT[0], sT[1]), fmaxf(sT[2], sT[3])),
                     fmaxf(fmaxf(sT[4], sT[5]), fmaxf(sT[6], sT[7])));
    pm = fmaxf(pm, fmaxf(fmaxf(fmaxf(sT[8], sT[9]), fmaxf(sT[10], sT[11])),
                         fmaxf(fmaxf(sT[12], sT[13]), fmaxf(sT[14], sT[15]))));
    { i32x2 r = pls(iasi(pm), iasi(pm)); pm = fmaxf(fasf(r[0]), fasf(r[1])); }

    if (!__all(pm - mS <= 8.0f)) {          // defer-max (THR=8)
      float mnew = fmaxf(mS, pm);
      float fsc = exp2f((mS - mnew) * L2E);
      mS = mnew;
      lS *= fsc;
      // redistribute fsc from lane-q to reg-rows via wave-private LDS broadcast
      if (hi == 0) *(float*)(smem + RBUFL + wid * 128 + rr * 4) = fsc;
      f32x4 fr[4];
#pragma unroll
      for (int i = 0; i < 4; ++i)
        fr[i] = *(const f32x4*)(smem + RBUFL + wid * 128 + i * 32 + hi * 16);
#pragma unroll
      for (int dt = 0; dt < 4; ++dt)
#pragma unroll
        for (int i = 0; i < 4; ++i)
#pragma unroll
          for (int j = 0; j < 4; ++j) O[dt][i * 4 + j] *= fr[i][j];
    }

    const float mL = mS * L2E;
    float pv[16];
#pragma unroll
    for (int r = 0; r < 16; ++r) pv[r] = exp2f(sT[r] * L2E - mL);
    float s01 = (pv[0] + pv[1]) + (pv[2] + pv[3]);
    float s23 = (pv[4] + pv[5]) + (pv[6] + pv[7]);
    float s45 = (pv[8] + pv[9]) + (pv[10] + pv[11]);
    float s67 = (pv[12] + pv[13]) + (pv[14] + pv[15]);
    float ts = (s01 + s23) + (s45 + s67);
    { i32x2 r = pls(iasi(ts), iasi(ts)); ts = fasf(r[0]) + fasf(r[1]); }
    lS += ts;

    // ---- V fragments (read late to cut live VGPRs) ----
    const char* vb = kb + 8192;
    short8 vf[2][4];
#pragma unroll
    for (int kt = 0; kt < 2; ++kt)
#pragma unroll
      for (int dt = 0; dt < 4; ++dt)
        vf[kt][dt] = *(const short8*)(vb + vfo[kt] + dt * 2048);

    // ---- P -> PV A-fragments fully in registers (T12) ----
    int dw[8];
#pragma unroll
    for (int m = 0; m < 8; ++m) dw[m] = cvtpk(pv[2 * m], pv[2 * m + 1]);
    i32x2 ra = pls(dw[0], dw[2]);
    i32x2 rb = pls(dw[1], dw[3]);
    i32x2 rc = pls(dw[4], dw[6]);
    i32x2 rd = pls(dw[5], dw[7]);
    i32x4 w0 = {ra[0], rb[0], ra[1], rb[1]};
    i32x4 w1 = {rc[0], rd[0], rc[1], rd[1]};
    short8 pa0 = __builtin_bit_cast(short8, w0);
    short8 pa1 = __builtin_bit_cast(short8, w1);

    // ---- PV: O[q][d] += P[q][kv] * V[kv][d] ----
    __builtin_amdgcn_s_setprio(1);
#pragma unroll
    for (int dt = 0; dt < 4; ++dt) {
      O[dt] = MFMA32(pa0, vf[0][dt], O[dt]);
      O[dt] = MFMA32(pa1, vf[1][dt], O[dt]);
    }
    __builtin_amdgcn_s_setprio(0);

    cur ^= 1;
  }

  // ---- in-LDS merge of the 4 kv-splits (per qsub group) ----
  __syncthreads();   // guard: overlay region overlaps staging buffers
  if (kvsub != 0 && hi == 0)
    *(float2*)(smem + MLOFF + (qsub * 3 + kvsub - 1) * 256 + rr * 8) =
        make_float2(mS, lS);
  __syncthreads();

  f32x4 crh[4][4], irv[4];
  if (kvsub == 0) {
    float mh[4], lh[4];
    mh[0] = mS; lh[0] = lS;
#pragma unroll
    for (int h = 1; h < 4; ++h) {
      float2 ml = *(const float2*)(smem + MLOFF + (qsub * 3 + h - 1) * 256 + rr * 8);
      mh[h] = ml.x; lh[h] = ml.y;
    }
    float M = fmaxf(fmaxf(mh[0], mh[1]), fmaxf(mh[2], mh[3]));
    float c[4], L = 0.f;
#pragma unroll
    for (int h = 0; h < 4; ++h) { c[h] = exp2f((mh[h] - M) * L2E); L += c[h] * lh[h]; }
    float iL = 1.0f / L;
    if (hi == 0) {
#pragma unroll
      for (int h = 0; h < 4; ++h)
        *(float*)(smem + CBUF + qsub * 512 + h * 128 + rr * 4) = c[h];
      *(float*)(smem + RB2 + qsub * 128 + rr * 4) = iL;
    }
#pragma unroll
    for (int i = 0; i < 4; ++i) {
#pragma unroll
      for (int h = 0; h < 4; ++h)
        crh[h][i] = *(const f32x4*)(smem + CBUF + qsub * 512 + h * 128 + i * 32 + hi * 16);
      irv[i] = *(const f32x4*)(smem + RB2 + qsub * 128 + i * 32 + hi * 16);
    }
  }

  unsigned short* og = Ag + (size_t)(b * 4096 + q0) * 128;
#pragma unroll
  for (int dt = 0; dt < 4; ++dt) {
    if (kvsub != 0) {
#pragma unroll
      for (int i = 0; i < 4; ++i) {
        f32x4 s = {O[dt][4 * i], O[dt][4 * i + 1], O[dt][4 * i + 2], O[dt][4 * i + 3]};
        *(f32x4*)(smem + MOOFF + (qsub * 3 + kvsub - 1) * 4096 + i * 1024 + lane * 16) = s;
      }
    }
    __syncthreads();
    if (kvsub == 0) {
#pragma unroll
      for (int i = 0; i < 4; ++i) {
        f32x4 o1 = *(const f32x4*)(smem + MOOFF + (qsub * 3 + 0) * 4096 + i * 1024 + lane * 16);
        f32x4 o2 = *(const f32x4*)(smem + MOOFF + (qsub * 3 + 1) * 4096 + i * 1024 + lane * 16);
        f32x4 o3 = *(const f32x4*)(smem + MOOFF + (qsub * 3 + 2) * 4096 + i * 1024 + lane * 16);
#pragma unroll
        for (int j = 0; j < 4; ++j) {
          float v = (crh[0][i][j] * O[dt][4 * i + j] + crh[1][i][j] * o1[j] +
                     crh[2][i][j] * o2[j] + crh[3][i][j] * o3[j]) * irv[i][j];
          int row = j + 8 * i + 4 * hi;
          og[row * 128 + dt * 32 + rr] = f2bf(v);
        }
      }
    }
    __syncthreads();
  }
}

// ---------------------------------------------------------------------------
// Kernel 3: out = attended @ Wo + bo  (fp32 output)
// ---------------------------------------------------------------------------
__global__ __launch_bounds__(256) void k_out(
    const unsigned short* __restrict__ Ag,
    const float* __restrict__ Wo, const float* __restrict__ bo,
    float* __restrict__ out)
{
  __shared__ __align__(16) unsigned short wt[128 * 128];
  const int tid = threadIdx.x, lane = tid & 63, wid = tid >> 6;
  const int l15 = lane & 15, g = lane >> 4;
  const int r0 = blockIdx.x * 64 + wid * 16;

  for (int i = 0; i < 64; ++i) {
    int idx = i * 256 + tid;
    int k = idx >> 7, n = idx & 127;
    int cs = (k >> 3) ^ (n & 7);
    wt[n * 128 + cs * 8 + (k & 7)] = f2bf(Wo[idx]);
  }

  short8 af[4];
  const unsigned short* ap = Ag + (r0 + l15) * 128 + g * 8;
#pragma unroll
  for (int kt = 0; kt < 4; ++kt) af[kt] = *(const short8*)(ap + kt * 32);

  float bias[8];
#pragma unroll
  for (int nt = 0; nt < 8; ++nt) bias[nt] = bo[nt * 16 + l15];

  __syncthreads();

  f32x4 acc[8];
#pragma unroll
  for (int nt = 0; nt < 8; ++nt) acc[nt] = (f32x4){0.f, 0.f, 0.f, 0.f};
#pragma unroll
  for (int nt = 0; nt < 8; ++nt) {
    int n = nt * 16 + l15;
#pragma unroll
    for (int ks = 0; ks < 4; ++ks) {
      int cs = (ks * 4 + g) ^ (n & 7);
      short8 bf = *(const short8*)&wt[n * 128 + cs * 8];
      acc[nt] = MFMA16(af[ks], bf, acc[nt]);
    }
  }
#pragma unroll
  for (int nt = 0; nt < 8; ++nt) {
    int col = nt * 16 + l15;
#pragma unroll
    for (int r = 0; r < 4; ++r)
      out[(r0 + g * 4 + r) * 128 + col] = acc[nt][r] + bias[nt];
  }
}

// ---------------------------------------------------------------------------
extern "C" void kernel_launch(void* const* d_in, const int* in_sizes, int n_in,
                              void* d_out, int out_size, void* d_ws, size_t ws_size,
                              hipStream_t stream) {
  const float* x  = (const float*)d_in[0];
  const float* Wq = (const float*)d_in[1];
  const float* bq = (const float*)d_in[2];
  const float* Wk = (const float*)d_in[3];
  const float* bk = (const float*)d_in[4];
  const float* Wv = (const float*)d_in[5];
  const float* bv = (const float*)d_in[6];
  const float* Wo = (const float*)d_in[7];
  const float* bo = (const float*)d_in[8];

  const int NTOK = 4 * 4096;               // B*S
  unsigned short* Qg  = (unsigned short*)d_ws;
  unsigned short* Kg  = Qg  + NTOK * 128;
  unsigned short* Vtg = Kg  + NTOK * 128;
  unsigned short* Ag  = Vtg + NTOK * 128;  // total 16 MB of d_ws

  k_proj<<<256, 256, 0, stream>>>(x, Wq, bq, Wk, bk, Wv, bv, Qg, Kg, Vtg);
  k_attn<<<256, 512, 0, stream>>>(Qg, Kg, Vtg, Ag);
  k_out<<<256, 256, 0, stream>>>(Ag, Wo, bo, (float*)d_out);
}

// Round 8
// 89.867 us; speedup vs baseline: 1.7750x; 1.0616x over previous
//
#include <hip/hip_runtime.h>
#include <stdint.h>

typedef __attribute__((ext_vector_type(8))) short short8;
typedef __attribute__((ext_vector_type(4))) float f32x4;
typedef __attribute__((ext_vector_type(16))) float f32x16;
typedef __attribute__((ext_vector_type(4))) int i32x4;
typedef __attribute__((ext_vector_type(2))) int i32x2;

#define MFMA16(a, b, c) __builtin_amdgcn_mfma_f32_16x16x32_bf16((a), (b), (c), 0, 0, 0)
#define MFMA32(a, b, c) __builtin_amdgcn_mfma_f32_32x32x16_bf16((a), (b), (c), 0, 0, 0)

#define L2E 1.4426950408889634f

__device__ __forceinline__ unsigned short f2bf(float f) {
  unsigned int u = __builtin_bit_cast(unsigned int, f);
  u += 0x7fffu + ((u >> 16) & 1u);   // RNE (finite values only)
  return (unsigned short)(u >> 16);
}

// permlane32_swap via builtin: two simultaneously-live results -> distinct regs
// guaranteed (inline-asm "+v","+v" self-swap was R3's bug).
__device__ __forceinline__ i32x2 pls(int a, int b) {
  return __builtin_amdgcn_permlane32_swap(a, b, false, false);
}
__device__ __forceinline__ float fasf(int x) { return __builtin_bit_cast(float, x); }
__device__ __forceinline__ int iasi(float x) { return __builtin_bit_cast(int, x); }

__device__ __forceinline__ int cvtpk(float lo, float hi) {
  int d;
  asm("v_cvt_pk_bf16_f32 %0, %1, %2" : "=v"(d) : "v"(lo), "v"(hi));
  return d;
}

// ---------------------------------------------------------------------------
// Kernel 1: Q/K/V projections, written in MFMA-fragment-ready tiled layouts:
//   Q2/K2: elem[(b*128 + tile)*4096 + kt*512 + (h>>3 &1)*256 + (s&31)*8 + (h&7)]
//          = M[s][h]   (tile = s>>5 within batch; kt = h>>4)
//   V2:    elem[(b*128 + tile)*4096 + ((s>>4)&1)*2048 + (d>>5)*512
//               + ((s>>3)&1)*256 + (d&31)*8 + (s&7)] = V[s][d]
//   Wo2:   elem[((oc>>5)*8 + (h>>4))*512 + ((h>>3)&1)*256 + (oc&31)*8 + (h&7)]
//          = Wo[h][oc]  (bf16; written by block 0)
// Q pre-scaled by 1/sqrt(128).
// ---------------------------------------------------------------------------
__global__ __launch_bounds__(256) void k_proj(
    const float* __restrict__ x,
    const float* __restrict__ Wq, const float* __restrict__ bq,
    const float* __restrict__ Wk, const float* __restrict__ bk,
    const float* __restrict__ Wv, const float* __restrict__ bv,
    const float* __restrict__ Wo,
    unsigned short* __restrict__ Q2, unsigned short* __restrict__ K2,
    unsigned short* __restrict__ V2, unsigned short* __restrict__ Wo2)
{
  __shared__ __align__(16) unsigned short wt[128 * 128];  // swizzled W^T, 32KB
  const int tid  = threadIdx.x;
  const int lane = tid & 63;
  const int wid  = tid >> 6;
  const int l15  = lane & 15;
  const int g    = lane >> 4;
  const int r0   = blockIdx.x * 64 + wid * 16;

  // Wo2 bf16 fragment-tiled copy (block 0 only; independent of the rest)
  if (blockIdx.x == 0) {
    for (int e = tid; e < 16384; e += 256) {
      int j = e & 7, ln = (e >> 3) & 63, kt = (e >> 9) & 7, dt = e >> 12;
      int h = kt * 16 + (ln >> 5) * 8 + j, oc = dt * 32 + (ln & 31);
      Wo2[e] = f2bf(Wo[h * 128 + oc]);
    }
  }

  short8 af[4];
  {
    const float* xp = x + (r0 + l15) * 128 + g * 8;
#pragma unroll
    for (int kt = 0; kt < 4; ++kt) {
      float4 v0 = *(const float4*)(xp + kt * 32);
      float4 v1 = *(const float4*)(xp + kt * 32 + 4);
      short8 a;
      a[0] = (short)f2bf(v0.x); a[1] = (short)f2bf(v0.y);
      a[2] = (short)f2bf(v0.z); a[3] = (short)f2bf(v0.w);
      a[4] = (short)f2bf(v1.x); a[5] = (short)f2bf(v1.y);
      a[6] = (short)f2bf(v1.z); a[7] = (short)f2bf(v1.w);
      af[kt] = a;
    }
  }

  const float* Ws[3] = {Wq, Wk, Wv};
  const float* bs[3] = {bq, bk, bv};

  for (int wI = 0; wI < 3; ++wI) {
    __syncthreads();
    const float* W = Ws[wI];
    for (int i = 0; i < 64; ++i) {
      int idx = i * 256 + tid;
      int k = idx >> 7, n = idx & 127;
      int cs = (k >> 3) ^ (n & 7);
      wt[n * 128 + cs * 8 + (k & 7)] = f2bf(W[idx]);
    }
    __syncthreads();

    float bias[8];
#pragma unroll
    for (int nt = 0; nt < 8; ++nt) bias[nt] = bs[wI][nt * 16 + l15];

    f32x4 acc[8];
#pragma unroll
    for (int nt = 0; nt < 8; ++nt) acc[nt] = (f32x4){0.f, 0.f, 0.f, 0.f};

#pragma unroll
    for (int nt = 0; nt < 8; ++nt) {
      const int n = nt * 16 + l15;
#pragma unroll
      for (int ks = 0; ks < 4; ++ks) {
        int cs = (ks * 4 + g) ^ (n & 7);
        short8 bf = *(const short8*)&wt[n * 128 + cs * 8];
        acc[nt] = MFMA16(af[ks], bf, acc[nt]);
      }
    }

    // D layout: col = nt*16 + l15 (h/d dim), row m = r0 + g*4 + r (s dim)
    if (wI < 2) {
      unsigned short* Og = (wI == 0) ? Q2 : K2;
      const float sc = (wI == 0) ? 0.08838834764831845f : 1.0f;  // 1/sqrt(128)
#pragma unroll
      for (int nt = 0; nt < 8; ++nt) {
        int col = nt * 16 + l15;
        int kt = col >> 4, hib = (col >> 3) & 1, jj = col & 7;
#pragma unroll
        for (int r = 0; r < 4; ++r) {
          int m = r0 + g * 4 + r;
          int bb = m >> 12, srow = m & 4095;
          int idx = (bb * 128 + (srow >> 5)) * 4096 + kt * 512 + hib * 256 +
                    (srow & 31) * 8 + jj;
          Og[idx] = f2bf((acc[nt][r] + bias[nt]) * sc);
        }
      }
    } else {
#pragma unroll
      for (int nt = 0; nt < 8; ++nt) {
        int col = nt * 16 + l15;
        int m0 = r0 + g * 4;
        int bb = m0 >> 12, srow = m0 & 4095;
        int idx = (bb * 128 + (srow >> 5)) * 4096 + ((srow >> 4) & 1) * 2048 +
                  (col >> 5) * 512 + ((srow >> 3) & 1) * 256 + (col & 31) * 8 +
                  (srow & 7);
        ushort4 pk;
        pk.x = f2bf(acc[nt][0] + bias[nt]);
        pk.y = f2bf(acc[nt][1] + bias[nt]);
        pk.z = f2bf(acc[nt][2] + bias[nt]);
        pk.w = f2bf(acc[nt][3] + bias[nt]);
        *(ushort4*)&V2[idx] = pk;
      }
    }
  }
}

// ---------------------------------------------------------------------------
// Kernel 2: fused flash attention + output projection.
// Grid 512 = (4 b) x (128 q-tiles of 32 rows); 256 thr = 4 waves; 2 blocks/CU.
// Wave w owns kv range [w*1024, (w+1)*1024), KVBLK=32, 32 iters.
// ALL operands loaded directly global->VGPR via fragment-tiled layouts
// (1KB coalesced per load). No LDS / barriers in the main loop.
// Swapped QK^T 32x32x16: lane = q, regs = kv; softmax + P in-register.
// Epilogue: 4-way merge (chunked via LDS) -> att_lds bf16 A-frag image ->
// all 4 waves compute att @ Wo2 + bo -> f32 out.
// ---------------------------------------------------------------------------
#define ATT   0
#define PART  8192
#define MLX   20480
#define CBUF  21248
#define RB2   21760
#define RBUF  21888

__global__ __launch_bounds__(256) void k_attn(
    const unsigned short* __restrict__ Q2,
    const unsigned short* __restrict__ K2,
    const unsigned short* __restrict__ V2,
    const unsigned short* __restrict__ Wo2,
    const float* __restrict__ bo,
    float* __restrict__ out)
{
  __shared__ __align__(16) char smem[22528];
  const int tid = threadIdx.x, lane = tid & 63, wid = tid >> 6;
  const int rr = lane & 31, hi = lane >> 5;
  // XCD-aware: batch b pinned to XCD pair {2b,2b+1}
  const int p = blockIdx.x;
  const int b = (p & 7) >> 1;
  const int qt = ((p >> 3) << 1) | (p & 1);   // 0..127

  // Q fragments: 8 coalesced 1KB loads
  short8 qf[8];
  {
    const unsigned short* qp = Q2 + (size_t)(b * 128 + qt) * 4096 + lane * 8;
#pragma unroll
    for (int kt = 0; kt < 8; ++kt) qf[kt] = *(const short8*)(qp + kt * 512);
  }

  const unsigned short* kp = K2 + (size_t)(b * 128 + wid * 32) * 4096 + lane * 8;
  const unsigned short* vp = V2 + (size_t)(b * 128 + wid * 32) * 4096 + lane * 8;

  short8 kf[8], vf[2][4];
#pragma unroll
  for (int kt = 0; kt < 8; ++kt) kf[kt] = *(const short8*)(kp + kt * 512);
#pragma unroll
  for (int k2 = 0; k2 < 2; ++k2)
#pragma unroll
    for (int dt = 0; dt < 4; ++dt)
      vf[k2][dt] = *(const short8*)(vp + k2 * 2048 + dt * 512);
  kp += 4096;
  vp += 4096;

  f32x16 O[4];
#pragma unroll
  for (int dt = 0; dt < 4; ++dt)
#pragma unroll
    for (int j = 0; j < 16; ++j) O[dt][j] = 0.f;
  f32x16 zc;
#pragma unroll
  for (int j = 0; j < 16; ++j) zc[j] = 0.f;
  float mS = -3.0e38f, lS = 0.f;

  for (int t = 0; t < 32; ++t) {
    // ---- QK^T swapped: D[kv=regs][q=lane&31], single accumulator chain ----
    __builtin_amdgcn_s_setprio(1);
    f32x16 sT = MFMA32(kf[0], qf[0], zc);
#pragma unroll
    for (int kt = 1; kt < 8; ++kt) sT = MFMA32(kf[kt], qf[kt], sT);
    __builtin_amdgcn_s_setprio(0);

    // prefetch next K tile (WAR on kf keeps order; vmcnt handled by compiler)
    if (t < 31) {
#pragma unroll
      for (int kt = 0; kt < 8; ++kt) kf[kt] = *(const short8*)(kp + kt * 512);
    }

    // ---- online softmax; kv row of reg r = (r&3)+8*(r>>2)+4*hi ----
    float pm = fmaxf(fmaxf(fmaxf(sT[0], sT[1]), fmaxf(sT[2], sT[3])),
                     fmaxf(fmaxf(sT[4], sT[5]), fmaxf(sT[6], sT[7])));
    pm = fmaxf(pm, fmaxf(fmaxf(fmaxf(sT[8], sT[9]), fmaxf(sT[10], sT[11])),
                         fmaxf(fmaxf(sT[12], sT[13]), fmaxf(sT[14], sT[15]))));
    { i32x2 r = pls(iasi(pm), iasi(pm)); pm = fmaxf(fasf(r[0]), fasf(r[1])); }

    if (!__all(pm - mS <= 8.0f)) {          // defer-max (THR=8)
      float mnew = fmaxf(mS, pm);
      float fsc = exp2f((mS - mnew) * L2E);
      mS = mnew;
      lS *= fsc;
      // redistribute fsc from lane-q to reg-rows via wave-private LDS bcast
      if (hi == 0) *(float*)(smem + RBUF + wid * 128 + rr * 4) = fsc;
      f32x4 fr[4];
#pragma unroll
      for (int i = 0; i < 4; ++i)
        fr[i] = *(const f32x4*)(smem + RBUF + wid * 128 + i * 32 + hi * 16);
#pragma unroll
      for (int dt = 0; dt < 4; ++dt)
#pragma unroll
        for (int i = 0; i < 4; ++i)
#pragma unroll
          for (int j = 0; j < 4; ++j) O[dt][i * 4 + j] *= fr[i][j];
    }

    const float mL = mS * L2E;
    float pv[16];
#pragma unroll
    for (int r = 0; r < 16; ++r) pv[r] = exp2f(sT[r] * L2E - mL);
    float s01 = (pv[0] + pv[1]) + (pv[2] + pv[3]);
    float s23 = (pv[4] + pv[5]) + (pv[6] + pv[7]);
    float s45 = (pv[8] + pv[9]) + (pv[10] + pv[11]);
    float s67 = (pv[12] + pv[13]) + (pv[14] + pv[15]);
    float ts = (s01 + s23) + (s45 + s67);
    { i32x2 r = pls(iasi(ts), iasi(ts)); ts = fasf(r[0]) + fasf(r[1]); }
    lS += ts;

    // ---- P -> PV A-fragments fully in registers (T12) ----
    int dw[8];
#pragma unroll
    for (int m = 0; m < 8; ++m) dw[m] = cvtpk(pv[2 * m], pv[2 * m + 1]);
    i32x2 ra = pls(dw[0], dw[2]);
    i32x2 rb = pls(dw[1], dw[3]);
    i32x2 rc = pls(dw[4], dw[6]);
    i32x2 rd = pls(dw[5], dw[7]);
    i32x4 w0 = {ra[0], rb[0], ra[1], rb[1]};
    i32x4 w1 = {rc[0], rd[0], rc[1], rd[1]};
    short8 pa0 = __builtin_bit_cast(short8, w0);
    short8 pa1 = __builtin_bit_cast(short8, w1);

    // ---- PV: O[q][d] += P[q][kv] * V[kv][d] ----
    __builtin_amdgcn_s_setprio(1);
#pragma unroll
    for (int dt = 0; dt < 4; ++dt) {
      O[dt] = MFMA32(pa0, vf[0][dt], O[dt]);
      O[dt] = MFMA32(pa1, vf[1][dt], O[dt]);
    }
    __builtin_amdgcn_s_setprio(0);

    // prefetch next V tile; advance pointers
    if (t < 31) {
#pragma unroll
      for (int k2 = 0; k2 < 2; ++k2)
#pragma unroll
        for (int dt = 0; dt < 4; ++dt)
          vf[k2][dt] = *(const short8*)(vp + k2 * 2048 + dt * 512);
      kp += 4096;
      vp += 4096;
    }
  }

  // ---- out-proj operand loads issued early (latency hidden under merge) ----
  short8 wof[8];
#pragma unroll
  for (int kt = 0; kt < 8; ++kt)
    wof[kt] = *(const short8*)(Wo2 + (wid * 8 + kt) * 512 + lane * 8);
  float bov = bo[wid * 32 + rr];

  // ---- 4-way kv-split merge (wave 0 merges), chunked by dt through LDS ----
  if (wid != 0 && hi == 0)
    *(float2*)(smem + MLX + (wid - 1) * 256 + rr * 8) = make_float2(mS, lS);
  __syncthreads();

  f32x4 crh[4][4], irv[4];
  if (wid == 0) {
    float mh[4], lh[4];
    mh[0] = mS; lh[0] = lS;
#pragma unroll
    for (int h = 1; h < 4; ++h) {
      float2 ml = *(const float2*)(smem + MLX + (h - 1) * 256 + rr * 8);
      mh[h] = ml.x; lh[h] = ml.y;
    }
    float M = fmaxf(fmaxf(mh[0], mh[1]), fmaxf(mh[2], mh[3]));
    float c[4], L = 0.f;
#pragma unroll
    for (int h = 0; h < 4; ++h) { c[h] = exp2f((mh[h] - M) * L2E); L += c[h] * lh[h]; }
    float iL = 1.0f / L;
    if (hi == 0) {
#pragma unroll
      for (int h = 0; h < 4; ++h) *(float*)(smem + CBUF + h * 128 + rr * 4) = c[h];
      *(float*)(smem + RB2 + rr * 4) = iL;
    }
#pragma unroll
    for (int i = 0; i < 4; ++i) {
#pragma unroll
      for (int h = 0; h < 4; ++h)
        crh[h][i] = *(const f32x4*)(smem + CBUF + h * 128 + i * 32 + hi * 16);
      irv[i] = *(const f32x4*)(smem + RB2 + i * 32 + hi * 16);
    }
  }

#pragma unroll
  for (int dt = 0; dt < 4; ++dt) {
    if (wid != 0) {
#pragma unroll
      for (int i = 0; i < 4; ++i) {
        f32x4 s = {O[dt][4 * i], O[dt][4 * i + 1], O[dt][4 * i + 2], O[dt][4 * i + 3]};
        *(f32x4*)(smem + PART + (wid - 1) * 4096 + i * 1024 + lane * 16) = s;
      }
    }
    __syncthreads();
    if (wid == 0) {
      int ktt = dt * 2 + (rr >> 4);
      int lt0 = ((rr >> 3) & 1) * 32;
      int jb  = (rr & 7) * 2;
#pragma unroll
      for (int i = 0; i < 4; ++i) {
        f32x4 o1 = *(const f32x4*)(smem + PART + 0 * 4096 + i * 1024 + lane * 16);
        f32x4 o2 = *(const f32x4*)(smem + PART + 1 * 4096 + i * 1024 + lane * 16);
        f32x4 o3 = *(const f32x4*)(smem + PART + 2 * 4096 + i * 1024 + lane * 16);
#pragma unroll
        for (int j = 0; j < 4; ++j) {
          float v = (crh[0][i][j] * O[dt][4 * i + j] + crh[1][i][j] * o1[j] +
                     crh[2][i][j] * o2[j] + crh[3][i][j] * o3[j]) * irv[i][j];
          int q = j + 8 * i + 4 * hi;
          *(unsigned short*)(smem + ATT + ktt * 1024 + (lt0 + q) * 16 + jb) = f2bf(v);
        }
      }
    }
    __syncthreads();
  }

  // ---- fused output projection: wave w computes out cols [w*32, w*32+32) ----
  short8 att[8];
#pragma unroll
  for (int kt = 0; kt < 8; ++kt)
    att[kt] = *(const short8*)(smem + ATT + kt * 1024 + lane * 16);

  __builtin_amdgcn_s_setprio(1);
  f32x16 acc = MFMA32(att[0], wof[0], zc);
#pragma unroll
  for (int kt = 1; kt < 8; ++kt) acc = MFMA32(att[kt], wof[kt], acc);
  __builtin_amdgcn_s_setprio(0);

  float* op = out + (size_t)(b * 4096 + qt * 32) * 128 + wid * 32 + rr;
#pragma unroll
  for (int r = 0; r < 16; ++r) {
    int q = (r & 3) + 8 * (r >> 2) + 4 * hi;
    op[q * 128] = acc[r] + bov;
  }
}

// ---------------------------------------------------------------------------
extern "C" void kernel_launch(void* const* d_in, const int* in_sizes, int n_in,
                              void* d_out, int out_size, void* d_ws, size_t ws_size,
                              hipStream_t stream) {
  const float* x  = (const float*)d_in[0];
  const float* Wq = (const float*)d_in[1];
  const float* bq = (const float*)d_in[2];
  const float* Wk = (const float*)d_in[3];
  const float* bk = (const float*)d_in[4];
  const float* Wv = (const float*)d_in[5];
  const float* bv = (const float*)d_in[6];
  const float* Wo = (const float*)d_in[7];
  const float* bo = (const float*)d_in[8];

  const int NE = 4 * 4096 * 128;           // elems per tensor (2M)
  unsigned short* Q2  = (unsigned short*)d_ws;
  unsigned short* K2  = Q2 + NE;
  unsigned short* V2  = K2 + NE;
  unsigned short* Wo2 = V2 + NE;           // +32KB

  k_proj<<<256, 256, 0, stream>>>(x, Wq, bq, Wk, bk, Wv, bv, Wo, Q2, K2, V2, Wo2);
  k_attn<<<512, 256, 0, stream>>>(Q2, K2, V2, Wo2, bo, (float*)d_out);
}

// Round 9
// 87.872 us; speedup vs baseline: 1.8153x; 1.0227x over previous
//
#include <hip/hip_runtime.h>
#include <stdint.h>

typedef __attribute__((ext_vector_type(8))) short short8;
typedef __attribute__((ext_vector_type(4))) float f32x4;
typedef __attribute__((ext_vector_type(16))) float f32x16;
typedef __attribute__((ext_vector_type(4))) int i32x4;
typedef __attribute__((ext_vector_type(2))) int i32x2;

#define MFMA16(a, b, c) __builtin_amdgcn_mfma_f32_16x16x32_bf16((a), (b), (c), 0, 0, 0)
#define MFMA32(a, b, c) __builtin_amdgcn_mfma_f32_32x32x16_bf16((a), (b), (c), 0, 0, 0)

#define L2E 1.4426950408889634f

__device__ __forceinline__ unsigned short f2bf(float f) {
  unsigned int u = __builtin_bit_cast(unsigned int, f);
  u += 0x7fffu + ((u >> 16) & 1u);   // RNE (finite values only)
  return (unsigned short)(u >> 16);
}

// permlane32_swap via builtin: two simultaneously-live results -> distinct regs
// guaranteed (inline-asm "+v","+v" self-swap was R3's bug).
__device__ __forceinline__ i32x2 pls(int a, int b) {
  return __builtin_amdgcn_permlane32_swap(a, b, false, false);
}
__device__ __forceinline__ float fasf(int x) { return __builtin_bit_cast(float, x); }
__device__ __forceinline__ int iasi(float x) { return __builtin_bit_cast(int, x); }

__device__ __forceinline__ int cvtpk(float lo, float hi) {
  int d;
  asm("v_cvt_pk_bf16_f32 %0, %1, %2" : "=v"(d) : "v"(lo), "v"(hi));
  return d;
}

// ---------------------------------------------------------------------------
// Kernel 1: Q/K/V projections, written in MFMA-fragment-ready tiled layouts:
//   Q2/K2: elem[(b*128 + tile)*4096 + kt*512 + ((h>>3)&1)*256 + (s&31)*8 + (h&7)]
//          = M[s][h]   (tile = s>>5 within batch; kt = h>>4)
//   V2:    elem[(b*128 + tile)*4096 + ((s>>4)&1)*2048 + (d>>5)*512
//               + ((s>>3)&1)*256 + (d&31)*8 + (s&7)] = V[s][d]
//   Wo2:   elem[((oc>>5)*8 + (h>>4))*512 + ((h>>3)&1)*256 + (oc&31)*8 + (h&7)]
//          = Wo[h][oc]  (bf16; written by block 0)
// Q pre-scaled by 1/sqrt(128).
// ---------------------------------------------------------------------------
__global__ __launch_bounds__(256) void k_proj(
    const float* __restrict__ x,
    const float* __restrict__ Wq, const float* __restrict__ bq,
    const float* __restrict__ Wk, const float* __restrict__ bk,
    const float* __restrict__ Wv, const float* __restrict__ bv,
    const float* __restrict__ Wo,
    unsigned short* __restrict__ Q2, unsigned short* __restrict__ K2,
    unsigned short* __restrict__ V2, unsigned short* __restrict__ Wo2)
{
  __shared__ __align__(16) unsigned short wt[128 * 128];  // swizzled W^T, 32KB
  const int tid  = threadIdx.x;
  const int lane = tid & 63;
  const int wid  = tid >> 6;
  const int l15  = lane & 15;
  const int g    = lane >> 4;
  const int r0   = blockIdx.x * 64 + wid * 16;

  // Wo2 bf16 fragment-tiled copy (block 0 only; independent of the rest)
  if (blockIdx.x == 0) {
    for (int e = tid; e < 16384; e += 256) {
      int j = e & 7, ln = (e >> 3) & 63, kt = (e >> 9) & 7, dt = e >> 12;
      int h = kt * 16 + (ln >> 5) * 8 + j, oc = dt * 32 + (ln & 31);
      Wo2[e] = f2bf(Wo[h * 128 + oc]);
    }
  }

  short8 af[4];
  {
    const float* xp = x + (r0 + l15) * 128 + g * 8;
#pragma unroll
    for (int kt = 0; kt < 4; ++kt) {
      float4 v0 = *(const float4*)(xp + kt * 32);
      float4 v1 = *(const float4*)(xp + kt * 32 + 4);
      short8 a;
      a[0] = (short)f2bf(v0.x); a[1] = (short)f2bf(v0.y);
      a[2] = (short)f2bf(v0.z); a[3] = (short)f2bf(v0.w);
      a[4] = (short)f2bf(v1.x); a[5] = (short)f2bf(v1.y);
      a[6] = (short)f2bf(v1.z); a[7] = (short)f2bf(v1.w);
      af[kt] = a;
    }
  }

  const float* Ws[3] = {Wq, Wk, Wv};
  const float* bs[3] = {bq, bk, bv};

  for (int wI = 0; wI < 3; ++wI) {
    __syncthreads();
    const float* W = Ws[wI];
    for (int i = 0; i < 64; ++i) {
      int idx = i * 256 + tid;
      int k = idx >> 7, n = idx & 127;
      int cs = (k >> 3) ^ (n & 7);
      wt[n * 128 + cs * 8 + (k & 7)] = f2bf(W[idx]);
    }
    __syncthreads();

    float bias[8];
#pragma unroll
    for (int nt = 0; nt < 8; ++nt) bias[nt] = bs[wI][nt * 16 + l15];

    f32x4 acc[8];
#pragma unroll
    for (int nt = 0; nt < 8; ++nt) acc[nt] = (f32x4){0.f, 0.f, 0.f, 0.f};

#pragma unroll
    for (int nt = 0; nt < 8; ++nt) {
      const int n = nt * 16 + l15;
#pragma unroll
      for (int ks = 0; ks < 4; ++ks) {
        int cs = (ks * 4 + g) ^ (n & 7);
        short8 bf = *(const short8*)&wt[n * 128 + cs * 8];
        acc[nt] = MFMA16(af[ks], bf, acc[nt]);
      }
    }

    // D layout: col = nt*16 + l15 (h/d dim), row m = r0 + g*4 + r (s dim)
    if (wI < 2) {
      unsigned short* Og = (wI == 0) ? Q2 : K2;
      const float sc = (wI == 0) ? 0.08838834764831845f : 1.0f;  // 1/sqrt(128)
#pragma unroll
      for (int nt = 0; nt < 8; ++nt) {
        int col = nt * 16 + l15;
        int kt = col >> 4, hib = (col >> 3) & 1, jj = col & 7;
#pragma unroll
        for (int r = 0; r < 4; ++r) {
          int m = r0 + g * 4 + r;
          int bb = m >> 12, srow = m & 4095;
          int idx = (bb * 128 + (srow >> 5)) * 4096 + kt * 512 + hib * 256 +
                    (srow & 31) * 8 + jj;
          Og[idx] = f2bf((acc[nt][r] + bias[nt]) * sc);
        }
      }
    } else {
#pragma unroll
      for (int nt = 0; nt < 8; ++nt) {
        int col = nt * 16 + l15;
        int m0 = r0 + g * 4;
        int bb = m0 >> 12, srow = m0 & 4095;
        int idx = (bb * 128 + (srow >> 5)) * 4096 + ((srow >> 4) & 1) * 2048 +
                  (col >> 5) * 512 + ((srow >> 3) & 1) * 256 + (col & 31) * 8 +
                  (srow & 7);
        ushort4 pk;
        pk.x = f2bf(acc[nt][0] + bias[nt]);
        pk.y = f2bf(acc[nt][1] + bias[nt]);
        pk.z = f2bf(acc[nt][2] + bias[nt]);
        pk.w = f2bf(acc[nt][3] + bias[nt]);
        *(ushort4*)&V2[idx] = pk;
      }
    }
  }
}

// ---------------------------------------------------------------------------
// Kernel 2: fused flash attention + output projection, BM=64.
// Grid 256 = (4 b) x (64 q-tiles of 64 rows); 512 thr = 8 waves; 1 block/CU.
// wave = (qsub = wid>>2, kvsub = wid&3): 32 q x 1024-kv quarter, KVBLK=32.
// The 2 qsub waves of each kvsub read the SAME K/V tiles -> L1 dedup (raw
// s_barrier per iter keeps them loosely aligned; no vmcnt drain).
// All operand loads direct global->VGPR via fragment-tiled layouts (1KB
// coalesced). Swapped QK^T 32x32x16: lane = q, regs = kv; softmax + P
// in-register. Epilogue: per-qsub 4-way merge (dt-chunked) -> att image ->
// 8-wave fused out-proj (wave -> out[qsub 32 rows][kvsub*32 cols]).
// ---------------------------------------------------------------------------
#define ATT   0        // 2 groups x 8KB
#define PART  16384    // 2 groups x 3 waves x 4KB
#define MLX   40960    // 2 groups x 3 x 256B
#define CBUF  42496    // 2 groups x 512B
#define RB2   43520    // 2 groups x 128B
#define RBUF  43776    // 8 waves x 128B

__global__ __launch_bounds__(512) void k_attn(
    const unsigned short* __restrict__ Q2,
    const unsigned short* __restrict__ K2,
    const unsigned short* __restrict__ V2,
    const unsigned short* __restrict__ Wo2,
    const float* __restrict__ bo,
    float* __restrict__ out)
{
  __shared__ __align__(16) char smem[45056];
  const int tid = threadIdx.x, lane = tid & 63, wid = tid >> 6;
  const int rr = lane & 31, hi = lane >> 5;
  const int qsub = wid >> 2, kvsub = wid & 3;
  // XCD-aware: batch b pinned to XCD pair {2b,2b+1}
  const int p = blockIdx.x;
  const int b = (p & 7) >> 1;
  const int qt = ((p >> 3) << 1) | (p & 1);   // 0..63

  // Q fragments: 8 coalesced 1KB loads (q-tile index = qt*2 + qsub)
  short8 qf[8];
  {
    const unsigned short* qp = Q2 + (size_t)(b * 128 + qt * 2 + qsub) * 4096 + lane * 8;
#pragma unroll
    for (int kt = 0; kt < 8; ++kt) qf[kt] = *(const short8*)(qp + kt * 512);
  }

  const unsigned short* kp = K2 + (size_t)(b * 128 + kvsub * 32) * 4096 + lane * 8;
  const unsigned short* vp = V2 + (size_t)(b * 128 + kvsub * 32) * 4096 + lane * 8;

  short8 kf[8], vf[2][4];
#pragma unroll
  for (int kt = 0; kt < 8; ++kt) kf[kt] = *(const short8*)(kp + kt * 512);
#pragma unroll
  for (int k2 = 0; k2 < 2; ++k2)
#pragma unroll
    for (int dt = 0; dt < 4; ++dt)
      vf[k2][dt] = *(const short8*)(vp + k2 * 2048 + dt * 512);
  kp += 4096;
  vp += 4096;

  f32x16 O[4];
#pragma unroll
  for (int dt = 0; dt < 4; ++dt)
#pragma unroll
    for (int j = 0; j < 16; ++j) O[dt][j] = 0.f;
  f32x16 zc;
#pragma unroll
  for (int j = 0; j < 16; ++j) zc[j] = 0.f;
  float mS = -3.0e38f, lS = 0.f;

  for (int t = 0; t < 32; ++t) {
    // ---- QK^T swapped: D[kv=regs][q=lane&31], single accumulator chain ----
    __builtin_amdgcn_s_setprio(1);
    f32x16 sT = MFMA32(kf[0], qf[0], zc);
#pragma unroll
    for (int kt = 1; kt < 8; ++kt) sT = MFMA32(kf[kt], qf[kt], sT);
    __builtin_amdgcn_s_setprio(0);

    // prefetch next K tile (WAR on kf keeps order; vmcnt handled by compiler)
    if (t < 31) {
#pragma unroll
      for (int kt = 0; kt < 8; ++kt) kf[kt] = *(const short8*)(kp + kt * 512);
    }
    // loose alignment of the qsub pair for L1 dedup (raw barrier, no drain)
    __builtin_amdgcn_s_barrier();

    // ---- online softmax; kv row of reg r = (r&3)+8*(r>>2)+4*hi ----
    float pm = fmaxf(fmaxf(fmaxf(sT[0], sT[1]), fmaxf(sT[2], sT[3])),
                     fmaxf(fmaxf(sT[4], sT[5]), fmaxf(sT[6], sT[7])));
    pm = fmaxf(pm, fmaxf(fmaxf(fmaxf(sT[8], sT[9]), fmaxf(sT[10], sT[11])),
                         fmaxf(fmaxf(sT[12], sT[13]), fmaxf(sT[14], sT[15]))));
    { i32x2 r = pls(iasi(pm), iasi(pm)); pm = fmaxf(fasf(r[0]), fasf(r[1])); }

    if (!__all(pm - mS <= 8.0f)) {          // defer-max (THR=8)
      float mnew = fmaxf(mS, pm);
      float fsc = exp2f((mS - mnew) * L2E);
      mS = mnew;
      lS *= fsc;
      // redistribute fsc from lane-q to reg-rows via wave-private LDS bcast
      if (hi == 0) *(float*)(smem + RBUF + wid * 128 + rr * 4) = fsc;
      f32x4 fr[4];
#pragma unroll
      for (int i = 0; i < 4; ++i)
        fr[i] = *(const f32x4*)(smem + RBUF + wid * 128 + i * 32 + hi * 16);
#pragma unroll
      for (int dt = 0; dt < 4; ++dt)
#pragma unroll
        for (int i = 0; i < 4; ++i)
#pragma unroll
          for (int j = 0; j < 4; ++j) O[dt][i * 4 + j] *= fr[i][j];
    }

    const float mL = mS * L2E;
    float pv[16];
#pragma unroll
    for (int r = 0; r < 16; ++r) pv[r] = exp2f(sT[r] * L2E - mL);
    float s01 = (pv[0] + pv[1]) + (pv[2] + pv[3]);
    float s23 = (pv[4] + pv[5]) + (pv[6] + pv[7]);
    float s45 = (pv[8] + pv[9]) + (pv[10] + pv[11]);
    float s67 = (pv[12] + pv[13]) + (pv[14] + pv[15]);
    float ts = (s01 + s23) + (s45 + s67);
    { i32x2 r = pls(iasi(ts), iasi(ts)); ts = fasf(r[0]) + fasf(r[1]); }
    lS += ts;

    // ---- P -> PV A-fragments fully in registers (T12) ----
    int dw[8];
#pragma unroll
    for (int m = 0; m < 8; ++m) dw[m] = cvtpk(pv[2 * m], pv[2 * m + 1]);
    i32x2 ra = pls(dw[0], dw[2]);
    i32x2 rb = pls(dw[1], dw[3]);
    i32x2 rc = pls(dw[4], dw[6]);
    i32x2 rd = pls(dw[5], dw[7]);
    i32x4 w0 = {ra[0], rb[0], ra[1], rb[1]};
    i32x4 w1 = {rc[0], rd[0], rc[1], rd[1]};
    short8 pa0 = __builtin_bit_cast(short8, w0);
    short8 pa1 = __builtin_bit_cast(short8, w1);

    // ---- PV: O[q][d] += P[q][kv] * V[kv][d] ----
    __builtin_amdgcn_s_setprio(1);
#pragma unroll
    for (int dt = 0; dt < 4; ++dt) {
      O[dt] = MFMA32(pa0, vf[0][dt], O[dt]);
      O[dt] = MFMA32(pa1, vf[1][dt], O[dt]);
    }
    __builtin_amdgcn_s_setprio(0);

    // prefetch next V tile; advance pointers
    if (t < 31) {
#pragma unroll
      for (int k2 = 0; k2 < 2; ++k2)
#pragma unroll
        for (int dt = 0; dt < 4; ++dt)
          vf[k2][dt] = *(const short8*)(vp + k2 * 2048 + dt * 512);
      kp += 4096;
      vp += 4096;
    }
  }

  // ---- out-proj operand loads issued early (latency hidden under merge) ----
  short8 wof[8];
#pragma unroll
  for (int kt = 0; kt < 8; ++kt)
    wof[kt] = *(const short8*)(Wo2 + (kvsub * 8 + kt) * 512 + lane * 8);
  float bov = bo[kvsub * 32 + rr];

  // ---- per-qsub 4-way kv-split merge (kvsub-0 wave merges), dt-chunked ----
  if (kvsub != 0 && hi == 0)
    *(float2*)(smem + MLX + (qsub * 3 + kvsub - 1) * 256 + rr * 8) =
        make_float2(mS, lS);
  __syncthreads();

  f32x4 crh[4][4], irv[4];
  if (kvsub == 0) {
    float mh[4], lh[4];
    mh[0] = mS; lh[0] = lS;
#pragma unroll
    for (int h = 1; h < 4; ++h) {
      float2 ml = *(const float2*)(smem + MLX + (qsub * 3 + h - 1) * 256 + rr * 8);
      mh[h] = ml.x; lh[h] = ml.y;
    }
    float M = fmaxf(fmaxf(mh[0], mh[1]), fmaxf(mh[2], mh[3]));
    float c[4], L = 0.f;
#pragma unroll
    for (int h = 0; h < 4; ++h) { c[h] = exp2f((mh[h] - M) * L2E); L += c[h] * lh[h]; }
    float iL = 1.0f / L;
    if (hi == 0) {
#pragma unroll
      for (int h = 0; h < 4; ++h)
        *(float*)(smem + CBUF + qsub * 512 + h * 128 + rr * 4) = c[h];
      *(float*)(smem + RB2 + qsub * 128 + rr * 4) = iL;
    }
#pragma unroll
    for (int i = 0; i < 4; ++i) {
#pragma unroll
      for (int h = 0; h < 4; ++h)
        crh[h][i] = *(const f32x4*)(smem + CBUF + qsub * 512 + h * 128 + i * 32 + hi * 16);
      irv[i] = *(const f32x4*)(smem + RB2 + qsub * 128 + i * 32 + hi * 16);
    }
  }

#pragma unroll
  for (int dt = 0; dt < 4; ++dt) {
    if (kvsub != 0) {
#pragma unroll
      for (int i = 0; i < 4; ++i) {
        f32x4 s = {O[dt][4 * i], O[dt][4 * i + 1], O[dt][4 * i + 2], O[dt][4 * i + 3]};
        *(f32x4*)(smem + PART + qsub * 12288 + (kvsub - 1) * 4096 + i * 1024 + lane * 16) = s;
      }
    }
    __syncthreads();
    if (kvsub == 0) {
      int ktt = dt * 2 + (rr >> 4);
      int lt0 = ((rr >> 3) & 1) * 32;
      int jb  = (rr & 7) * 2;
#pragma unroll
      for (int i = 0; i < 4; ++i) {
        f32x4 o1 = *(const f32x4*)(smem + PART + qsub * 12288 + 0 * 4096 + i * 1024 + lane * 16);
        f32x4 o2 = *(const f32x4*)(smem + PART + qsub * 12288 + 1 * 4096 + i * 1024 + lane * 16);
        f32x4 o3 = *(const f32x4*)(smem + PART + qsub * 12288 + 2 * 4096 + i * 1024 + lane * 16);
#pragma unroll
        for (int j = 0; j < 4; ++j) {
          float v = (crh[0][i][j] * O[dt][4 * i + j] + crh[1][i][j] * o1[j] +
                     crh[2][i][j] * o2[j] + crh[3][i][j] * o3[j]) * irv[i][j];
          int q = j + 8 * i + 4 * hi;
          *(unsigned short*)(smem + ATT + qsub * 8192 + ktt * 1024 + (lt0 + q) * 16 + jb) = f2bf(v);
        }
      }
    }
    __syncthreads();
  }

  // ---- fused output projection: wave (qsub,kvsub) -> out rows of qsub,
  //      cols [kvsub*32, kvsub*32+32) ----
  short8 att[8];
#pragma unroll
  for (int kt = 0; kt < 8; ++kt)
    att[kt] = *(const short8*)(smem + ATT + qsub * 8192 + kt * 1024 + lane * 16);

  __builtin_amdgcn_s_setprio(1);
  f32x16 acc = MFMA32(att[0], wof[0], zc);
#pragma unroll
  for (int kt = 1; kt < 8; ++kt) acc = MFMA32(att[kt], wof[kt], acc);
  __builtin_amdgcn_s_setprio(0);

  float* op = out + (size_t)(b * 4096 + qt * 64 + qsub * 32) * 128 + kvsub * 32 + rr;
#pragma unroll
  for (int r = 0; r < 16; ++r) {
    int q = (r & 3) + 8 * (r >> 2) + 4 * hi;
    op[q * 128] = acc[r] + bov;
  }
}

// ---------------------------------------------------------------------------
extern "C" void kernel_launch(void* const* d_in, const int* in_sizes, int n_in,
                              void* d_out, int out_size, void* d_ws, size_t ws_size,
                              hipStream_t stream) {
  const float* x  = (const float*)d_in[0];
  const float* Wq = (const float*)d_in[1];
  const float* bq = (const float*)d_in[2];
  const float* Wk = (const float*)d_in[3];
  const float* bk = (const float*)d_in[4];
  const float* Wv = (const float*)d_in[5];
  const float* bv = (const float*)d_in[6];
  const float* Wo = (const float*)d_in[7];
  const float* bo = (const float*)d_in[8];

  const int NE = 4 * 4096 * 128;           // elems per tensor (2M)
  unsigned short* Q2  = (unsigned short*)d_ws;
  unsigned short* K2  = Q2 + NE;
  unsigned short* V2  = K2 + NE;
  unsigned short* Wo2 = V2 + NE;           // +32KB

  k_proj<<<256, 256, 0, stream>>>(x, Wq, bq, Wk, bk, Wv, bv, Wo, Q2, K2, V2, Wo2);
  k_attn<<<256, 512, 0, stream>>>(Q2, K2, V2, Wo2, bo, (float*)d_out);
}